// Round 2
// baseline (1091.201 us; speedup 1.0000x reference)
//
#include <hip/hip_runtime.h>

// GAT attention aggregator — all-register streaming form (v2).
//   relu(h_self + sum_r coef_r (X@W)_r + b) = relu((self + sum_r coef_r X_r)@W + b)
//   prep : wa = W@a (128 floats), Wt = W^T bf16 (for the epilogue GEMM)
//   pass1: per node, lane (q,l15) naturally owns cols [8*l15,8*l15+8) of rows
//          q+4c (c=0..7) via 16 coalesced float4 loads. Logits, leaky_relu,
//          softmax, and z = coef^T X are computed entirely in registers with
//          butterfly shuffles — NO LDS, NO MFMA, NO bf16 conversion, ~110 VGPR
//          (previous versions spilled their staging regs to scratch -> 3x HBM
//          traffic; this version is spill-proof by construction).
//          Writes y = self + z into `out`. Memory-bound: ~870 MB total.
//   pass2: out = relu(Y@W + b), dense bf16 MFMA GEMM, in-place per 16-row
//          panel (each wave reads only rows it writes), hi/lo-compensated A.

constexpr int D  = 128;
constexpr int KN = 32;

typedef __bf16 bf16;
typedef __attribute__((ext_vector_type(8))) __bf16 bf16x8;
typedef __attribute__((ext_vector_type(4))) float  f32x4;

// ---- one-shot prep: Wt[n][k] = W[k][n] (bf16), wa[k] = sum_n W[k][n] a[n] ----
__global__ void prep_kernel(const float* __restrict__ W,
                            const float* __restrict__ attn,
                            bf16* __restrict__ Wt,
                            float* __restrict__ wa)
{
  const int i = blockIdx.x * 256 + threadIdx.x;
  if (i < D * D) {
    const int n = i >> 7, k = i & 127;
    Wt[i] = (bf16)W[(k << 7) + n];
  }
  if (i < D) {
    float s = 0.f;
    for (int n = 0; n < D; ++n) s += W[i * D + n] * attn[n];
    wa[i] = s;
  }
}

// ---- pass 1: streaming attention, all in registers ----
__global__ __launch_bounds__(256, 3)
void gat_pass1(const float* __restrict__ selfv,
               const float* __restrict__ neighv,
               const float* __restrict__ Wfp,
               const float* __restrict__ attnv,
               const float* __restrict__ wa_g,
               float* __restrict__ ybuf,
               int nnodes, int npn, int use_ws)
{
  const int tid  = threadIdx.x;
  const int w    = tid >> 6;
  const int lane = tid & 63;
  const int q    = lane >> 4;
  const int l15  = lane & 15;

  // per-lane wa slice: cols [8*l15, 8*l15+8)
  float wr[8];
  if (use_ws) {
    const float4 a = *(const float4*)&wa_g[8 * l15];
    const float4 b = *(const float4*)&wa_g[8 * l15 + 4];
    wr[0] = a.x; wr[1] = a.y; wr[2] = a.z; wr[3] = a.w;
    wr[4] = b.x; wr[5] = b.y; wr[6] = b.z; wr[7] = b.w;
  } else {
    #pragma unroll
    for (int j = 0; j < 8; ++j) {
      float s = 0.f;
      for (int n = 0; n < D; ++n) s += Wfp[(8 * l15 + j) * D + n] * attnv[n];
      wr[j] = s;
    }
  }

  const float4* neigh4 = (const float4*)neighv;
  const float4* self4  = (const float4*)selfv;
  const int base = (blockIdx.x * 4 + w) * npn;

  for (int i = 0; i < npn; ++i) {
    const int node = base + i;
    if (node >= nnodes) break;               // wave-uniform

    // ---- load: lane gets cols [8*l15,8*l15+8) of rows q+4c, c=0..7 ----
    float4 st[16];
    const size_t nb = (size_t)node * (KN * D / 4);
    #pragma unroll
    for (int c = 0; c < 8; ++c) {
      st[2 * c]     = neigh4[nb + 2 * (lane + 64 * c)];
      st[2 * c + 1] = neigh4[nb + 2 * (lane + 64 * c) + 1];
    }
    const float4 s0 = self4[(size_t)node * (D / 4) + 2 * l15];
    const float4 s1 = self4[(size_t)node * (D / 4) + 2 * l15 + 1];

    // ---- logit partials: pl[c] = X[q+4c][8l15..+8] . wr ----
    float pl[8];
    #pragma unroll
    for (int c = 0; c < 8; ++c) {
      const float4 a = st[2 * c], b = st[2 * c + 1];
      pl[c] = a.x * wr[0] + a.y * wr[1] + a.z * wr[2] + a.w * wr[3]
            + b.x * wr[4] + b.y * wr[5] + b.z * wr[6] + b.w * wr[7];
    }
    // reduce over the 16 l15 lanes -> pl[c] = logit[row q+4c], replicated
    #pragma unroll
    for (int m = 1; m < 16; m <<= 1)
      #pragma unroll
      for (int c = 0; c < 8; ++c)
        pl[c] += __shfl_xor(pl[c], m);

    // ---- self logit ----
    float sl = s0.x * wr[0] + s0.y * wr[1] + s0.z * wr[2] + s0.w * wr[3]
             + s1.x * wr[4] + s1.y * wr[5] + s1.z * wr[6] + s1.w * wr[7];
    sl += __shfl_xor(sl, 1); sl += __shfl_xor(sl, 2);
    sl += __shfl_xor(sl, 4); sl += __shfl_xor(sl, 8);

    // ---- leaky_relu + softmax over 32 rows (rows q+4c live in q-group q) ----
    float t[8], mx = -3.4e38f;
    #pragma unroll
    for (int c = 0; c < 8; ++c) {
      float v = pl[c] + sl;
      v = v > 0.f ? v : 0.2f * v;
      t[c] = v;
      mx = fmaxf(mx, v);
    }
    mx = fmaxf(mx, __shfl_xor(mx, 16));
    mx = fmaxf(mx, __shfl_xor(mx, 32));
    float s = 0.f;
    #pragma unroll
    for (int c = 0; c < 8; ++c) {
      t[c] = __expf(t[c] - mx);
      s += t[c];
    }
    s += __shfl_xor(s, 16);
    s += __shfl_xor(s, 32);
    const float inv = 1.0f / s;

    // ---- z[j] = sum_c t[c] * X[q+4c][8l15+j], reduce over q-groups ----
    float z[8] = {0.f, 0.f, 0.f, 0.f, 0.f, 0.f, 0.f, 0.f};
    #pragma unroll
    for (int c = 0; c < 8; ++c) {
      const float4 a = st[2 * c], b = st[2 * c + 1];
      z[0] += t[c] * a.x; z[1] += t[c] * a.y;
      z[2] += t[c] * a.z; z[3] += t[c] * a.w;
      z[4] += t[c] * b.x; z[5] += t[c] * b.y;
      z[6] += t[c] * b.z; z[7] += t[c] * b.w;
    }
    #pragma unroll
    for (int j = 0; j < 8; ++j) {
      z[j] += __shfl_xor(z[j], 16);
      z[j] += __shfl_xor(z[j], 32);
    }

    // ---- y = self + inv*z ; q=0 stores cols [8l15,+4), q=1 stores [8l15+4,+4) ----
    if (q == 0) {
      const float4 y = { s0.x + inv * z[0], s0.y + inv * z[1],
                         s0.z + inv * z[2], s0.w + inv * z[3] };
      *(float4*)&ybuf[(size_t)node * D + 8 * l15] = y;
    } else if (q == 1) {
      const float4 y = { s1.x + inv * z[4], s1.y + inv * z[5],
                         s1.z + inv * z[6], s1.w + inv * z[7] };
      *(float4*)&ybuf[(size_t)node * D + 8 * l15 + 4] = y;
    }
  }
}

// ---- pass 2: out = relu(Y @ W + bias), in-place per 16-row panel.
//      A operand double-bf16 compensated (hi+lo) so Y rounding ~ fp32. ----
__global__ __launch_bounds__(256, 2)
void gat_pass2(const bf16* __restrict__ Wt_g,
               const float* __restrict__ Wfp,
               const float* __restrict__ biasp,
               float* __restrict__ out,
               int nnodes, int use_ws)
{
  const int tid = threadIdx.x, w = tid >> 6, lane = tid & 63;
  const int q = lane >> 4, l15 = lane & 15;
  const int t = blockIdx.x * 4 + w;
  const int row0 = t * 16;
  if (row0 >= nnodes) return;

  float bv[8];
  #pragma unroll
  for (int nt = 0; nt < 8; ++nt) bv[nt] = biasp[nt * 16 + l15];

  const int arow = row0 + l15;
  const bool rv = arow < nnodes;

  f32x4 acc[8];
  #pragma unroll
  for (int nt = 0; nt < 8; ++nt) acc[nt] = (f32x4){0.f, 0.f, 0.f, 0.f};

  #pragma unroll
  for (int ks = 0; ks < 4; ++ks) {
    float a[8];
    if (rv) {
      const float4 v0 = *(const float4*)&out[(size_t)arow * D + ks * 32 + q * 8];
      const float4 v1 = *(const float4*)&out[(size_t)arow * D + ks * 32 + q * 8 + 4];
      a[0] = v0.x; a[1] = v0.y; a[2] = v0.z; a[3] = v0.w;
      a[4] = v1.x; a[5] = v1.y; a[6] = v1.z; a[7] = v1.w;
    } else {
      #pragma unroll
      for (int j = 0; j < 8; ++j) a[j] = 0.f;
    }
    bf16x8 Ah, Al;
    #pragma unroll
    for (int j = 0; j < 8; ++j) {
      const bf16 h = (bf16)a[j];
      Ah[j] = h;
      Al[j] = (bf16)(a[j] - (float)h);
    }
    #pragma unroll
    for (int nt = 0; nt < 8; ++nt) {
      bf16x8 B;
      if (use_ws) {
        B = *(const bf16x8*)&Wt_g[(nt * 16 + l15) * D + ks * 32 + q * 8];
      } else {
        #pragma unroll
        for (int j = 0; j < 8; ++j)
          B[j] = (bf16)Wfp[(size_t)(ks * 32 + q * 8 + j) * D + nt * 16 + l15];
      }
      acc[nt] = __builtin_amdgcn_mfma_f32_16x16x32_bf16(Ah, B, acc[nt], 0, 0, 0);
      acc[nt] = __builtin_amdgcn_mfma_f32_16x16x32_bf16(Al, B, acc[nt], 0, 0, 0);
    }
  }

  #pragma unroll
  for (int nt = 0; nt < 8; ++nt) {
    #pragma unroll
    for (int r = 0; r < 4; ++r) {
      const int row = row0 + q * 4 + r;
      if (row < nnodes)
        out[(size_t)row * D + nt * 16 + l15] = fmaxf(acc[nt][r] + bv[nt], 0.f);
    }
  }
}

extern "C" void kernel_launch(void* const* d_in, const int* in_sizes, int n_in,
                              void* d_out, int out_size, void* d_ws, size_t ws_size,
                              hipStream_t stream) {
  const float* selfv  = (const float*)d_in[0];
  const float* neighv = (const float*)d_in[1];
  const float* W      = (const float*)d_in[2];
  const float* attn   = (const float*)d_in[3];
  const float* biasp  = (const float*)d_in[4];
  float* out = (float*)d_out;
  const int nnodes = in_sizes[0] / D;

  const size_t need = (size_t)D * D * sizeof(bf16) + D * sizeof(float);
  const int use_ws = (ws_size >= need) ? 1 : 0;
  bf16*  Wt_g = (bf16*)d_ws;
  float* wa_g = (float*)((char*)d_ws + (size_t)D * D * sizeof(bf16));
  if (use_ws)
    prep_kernel<<<(D * D + 255) / 256, 256, 0, stream>>>(W, attn, Wt_g, wa_g);

  // pass1: 768 blocks x 4 waves = 3072 waves, npn nodes each, no LDS
  const int nwaves = 3072;
  const int npn    = (nnodes + nwaves - 1) / nwaves;
  gat_pass1<<<nwaves / 4, 256, 0, stream>>>(selfv, neighv, W, attn, wa_g, out,
                                            nnodes, npn, use_ws);

  // pass2: 16-row panels, 4 per block
  const int ntiles = (nnodes + 15) / 16;
  gat_pass2<<<(ntiles + 3) / 4, 256, 0, stream>>>(Wt_g, W, biasp, out,
                                                  nnodes, use_ws);
}